// Round 5
// baseline (140.884 us; speedup 1.0000x reference)
//
#include <hip/hip_runtime.h>
#include <cstdint>

// CIN chain: B=1024, F0=32, EMB=64, layers 128/128/128.
// cur[b,k,e] = sum_{i,j} x[b,i,e]*h[b,j,e]*W[i*fi+j,k]
//
// R19: UNCHOKE REGISTERS. R18 post-mortem: WRITE fixed (24 MB, not
// binding at 460 GB/s) but VALU/wave ~12K vs ~2K expected, with
// VGPR_Count=64. Both __launch_bounds__(256,4) kernels (R16: 60 VGPR /
// 50% VALUBusy; R18: 64 / 37%) were register-starved -> the ~115-reg
// kloop live set spilled to AGPRs and v_accvgpr churn dominated VALU.
// R17's (128,2) gave 92 VGPR + VALUBusy 11% with the same addressing.
// Changes vs R18 (single-variable test of the starvation theory):
//  * cin_fused __launch_bounds__(256,4) -> (256,2): VGPR cap 256,
//    expect ~95-130 alloc; 4 blocks/CU still possible (LDS 38912*4
//    = 152 KB) if alloc <= 128.
//  * remove #pragma unroll from the chunk loop (full unroll inflated
//    live ranges; R17's un-pragma'd loop was the clean codegen).
// Structure unchanged: 1 batch/block, 4 waves (ms,kh) = M-split-2 x
// K-split-2, template NCH/ISH/PH addressing, f32 LDS exchange,
// sgemm tiles split across 4 waves, K-split-4 cin_direct.
// LDS (38912 B): sX 4K | R_A 9216 | R_B 9216 | XC 16K
//   R_A hT0(p40) -> [B1] -> hJ1(p72)
//   R_B xJ(p72)  -> [B1] -> hT1(p72) -> [B3] -> hJ2(p72)

typedef _Float16 half8  __attribute__((ext_vector_type(8)));
typedef _Float16 half4_ __attribute__((ext_vector_type(4)));
typedef _Float16 half2_ __attribute__((ext_vector_type(2)));
typedef float    f32x4  __attribute__((ext_vector_type(4)));

// Pack W (fan_in,128) f32 -> chunked f16 Wt[c][m][kk] = W[c*32+kk][m].
__global__ void pack_w_all(const float* __restrict__ W0, _Float16* __restrict__ Wt0,
                           const float* __restrict__ W1, _Float16* __restrict__ Wt1,
                           const float* __restrict__ W2, _Float16* __restrict__ Wt2)
{
    __shared__ _Float16 ldsT[128 * 33];
    const int blk = blockIdx.x, t = threadIdx.x;
    const float* W;
    _Float16* Wt;
    int c;
    if (blk < 32)       { W = W0; Wt = Wt0; c = blk; }
    else if (blk < 96)  { W = W1; Wt = Wt1; c = blk - 32; }
    else                { W = W2; Wt = Wt2; c = blk - 96; }

    for (int p = t; p < 32 * 128; p += 256) {
        int kk = p >> 7, m = p & 127;
        ldsT[m * 33 + kk] = (_Float16)W[(size_t)(c * 32 + kk) * 128 + m];
    }
    __syncthreads();
    int m = t >> 1, kk0 = (t & 1) * 16;
    half8 v0, v1;
#pragma unroll
    for (int i = 0; i < 8; ++i) {
        v0[i] = ldsT[m * 33 + kk0 + i];
        v1[i] = ldsT[m * 33 + kk0 + 8 + i];
    }
    *(half8*)(Wt + (size_t)c * 4096 + t * 16)     = v0;
    *(half8*)(Wt + (size_t)c * 4096 + t * 16 + 8) = v1;
}

// Templated kloop: rows ms*32..+31 (mt=2), K-half kh.
template<int NCH, int ISH, int PH>
__device__ __forceinline__ void kloop_t(f32x4 (&acc)[2][4],
    const _Float16* __restrict__ WtL, const _Float16* __restrict__ hb,
    const _Float16* __restrict__ sX, int lr, int q, int ms, int kh)
{
#pragma unroll
    for (int mt = 0; mt < 2; ++mt)
#pragma unroll
        for (int nt = 0; nt < 4; ++nt)
            acc[mt][nt] = f32x4{0.0f, 0.0f, 0.0f, 0.0f};

    constexpr int HC = NCH / 2;               // chunks per wave
    const int c0 = kh * HC;
    const _Float16* aG = WtL + (size_t)c0 * 4096 + (ms * 32 + lr) * 32 + q * 8;
    const _Float16* hP = hb + lr * PH + q * 8;
    const _Float16* xP = sX + lr;

    half8 afA[2], afB[2], hvA[4], hvB[4];
    _Float16 xsA[4], xsB[4];

    auto pf = [&](half8* af, half8* hv, _Float16* xs, int cc) {
        const int c  = c0 + cc;
        const int i  = c >> ISH;
        const int j0 = (c & ((1 << ISH) - 1)) << 5;
        const _Float16* ag = aG + (size_t)cc * 4096;
        af[0] = *(const half8*)(ag);
        af[1] = *(const half8*)(ag + 512);
        const _Float16* hh = hP + j0;
        const _Float16* xb = xP + (i << 6);
#pragma unroll
        for (int nt = 0; nt < 4; ++nt) {
            hv[nt] = *(const half8*)(hh + nt * (PH * 16));
            xs[nt] = xb[nt * 16];
        }
    };
    auto cp = [&](half8* af, half8* hv, _Float16* xs) {
#pragma unroll
        for (int nt = 0; nt < 4; ++nt) {
            half2_ xv2 = {xs[nt], xs[nt]};
            half8 xv8 = __builtin_shufflevector(xv2, xv2, 0, 1, 0, 1, 0, 1, 0, 1);
            half8 bf = hv[nt] * xv8;
            acc[0][nt] = __builtin_amdgcn_mfma_f32_16x16x32_f16(
                af[0], bf, acc[0][nt], 0, 0, 0);
            acc[1][nt] = __builtin_amdgcn_mfma_f32_16x16x32_f16(
                af[1], bf, acc[1][nt], 0, 0, 0);
        }
    };

    pf(afA, hvA, xsA, 0);
    for (int cc = 0; cc < HC; cc += 2) {
        pf(afB, hvB, xsB, cc + 1);
        cp(afA, hvA, xsA);
        if (cc + 2 < HC) pf(afA, hvA, xsA, cc + 2);
        cp(afB, hvB, xsB);
    }
}

// Fused hidden+S kernel. Block = 1 batch, 256 thr = 4 waves (ms,kh).
__global__ __launch_bounds__(256, 2)
void cin_fused(const float* __restrict__ x,          // (1024,32,64) f32
               const _Float16* __restrict__ Wt0,
               const _Float16* __restrict__ Wt1,
               const float* __restrict__ bs0,
               const float* __restrict__ bs1,
               _Float16* __restrict__ S0,             // (1024,1024)
               _Float16* __restrict__ S1,             // (1024,2048)
               _Float16* __restrict__ S2)             // (1024,2048)
{
    __shared__ alignas(16) char smem[38912];
    _Float16* sX  = (_Float16*)smem;                   // 4 KB  [i*64+e]
    _Float16* R_A = (_Float16*)(smem + 4096);          // 9216 B
    _Float16* R_B = (_Float16*)(smem + 13312);         // 9216 B
    f32x4*    XC  = (f32x4*)   (smem + 22528);         // 16 KB exchange

    const int t = threadIdx.x, lane = t & 63, w = t >> 6;
    const int ms = w >> 1, kh = w & 1;
    const int lr = lane & 15, q = lane >> 4;
    const int b = blockIdx.x;

    // prologue: x -> sX [i][e]; xJ (pitch 72) -> R_B; hT0 (pitch 40) -> R_A
    {
        const float4* xv = (const float4*)(x + (size_t)b * 2048);
#pragma unroll
        for (int s = 0; s < 2; ++s) {
            int p4 = t + s * 256;
            float4 v = xv[p4];
            int idx = p4 * 4, i = idx >> 6, e0 = idx & 63;
            _Float16 h0 = (_Float16)v.x, h1 = (_Float16)v.y;
            _Float16 h2 = (_Float16)v.z, h3 = (_Float16)v.w;
            half4_ pk = {h0, h1, h2, h3};
            *(half4_*)(sX + i * 64 + e0) = pk;
            *(half4_*)(R_B + i * 72 + e0) = pk;
            R_A[(e0 + 0) * 40 + i] = h0;
            R_A[(e0 + 1) * 40 + i] = h1;
            R_A[(e0 + 2) * 40 + i] = h2;
            R_A[(e0 + 3) * 40 + i] = h3;
        }
    }
    __syncthreads();                                   // B0

    // persistent sgemm A-fragments: x rows it*16+lr, e = q*8 .. (+32)
    half8 aF[2][2];
#pragma unroll
    for (int it = 0; it < 2; ++it) {
        aF[it][0] = *(const half8*)(R_B + (it * 16 + lr) * 72 + q * 8);
        aF[it][1] = *(const half8*)(R_B + (it * 16 + lr) * 72 + q * 8 + 32);
    }

    f32x4 acc[2][4];

    // exchange: wave (ms,kh) writes acc[1-kh], reads partner (ms,1-kh).
    const int wslot = ms * 2 + kh, pslot = ms * 2 + (1 - kh);
    auto xw = [&](const f32x4 (&a)[4]) {
#pragma unroll
        for (int nt = 0; nt < 4; ++nt)
            XC[wslot * 256 + nt * 64 + lane] = a[nt];
    };
    auto xr = [&](f32x4 (&a)[4]) {
#pragma unroll
        for (int nt = 0; nt < 4; ++nt)
            a[nt] += XC[pslot * 256 + nt * 64 + lane];
    };

    // S_l[b][i*fi+j] = sum_e x[i,e]*h[j,e]; tiles split across 4 waves
    auto sgemm = [&](const _Float16* hJ, int fi, _Float16* Sdst) {
        const int nT = fi >> 3;                        // 4 or 8 tiles
        for (int tt = w; tt < nT; tt += 4) {
            const int it = tt & 1, jt = tt >> 1;
            f32x4 sa = {0.0f, 0.0f, 0.0f, 0.0f};
            half8 bv0 = *(const half8*)(hJ + (jt * 16 + lr) * 72 + q * 8);
            half8 bv1 = *(const half8*)(hJ + (jt * 16 + lr) * 72 + q * 8 + 32);
            sa = __builtin_amdgcn_mfma_f32_16x16x32_f16(aF[it][0], bv0, sa, 0, 0, 0);
            sa = __builtin_amdgcn_mfma_f32_16x16x32_f16(aF[it][1], bv1, sa, 0, 0, 0);
#pragma unroll
            for (int r = 0; r < 4; ++r)
                Sdst[(size_t)b * (32 * fi) + (it * 16 + q * 4 + r) * fi
                     + jt * 16 + lr] = (_Float16)sa[r];
        }
    };

    // epilogue for this wave's 16 rows (ms*32 + kh*16 + q*4 ..)
    auto epi_rows = [&](const f32x4 (&a)[4], const float* bs,
                        _Float16* hJ, _Float16* hT, bool wantT) {
        const int jb = ms * 32 + kh * 16 + q * 4;
        const float b0f = bs[jb + 0], b1f = bs[jb + 1];
        const float b2f = bs[jb + 2], b3f = bs[jb + 3];
#pragma unroll
        for (int nt = 0; nt < 4; ++nt) {
            const int e = nt * 16 + lr;
            half4_ vh;
            vh[0] = (_Float16)(a[nt][0] + b0f);
            vh[1] = (_Float16)(a[nt][1] + b1f);
            vh[2] = (_Float16)(a[nt][2] + b2f);
            vh[3] = (_Float16)(a[nt][3] + b3f);
            hJ[(jb + 0) * 72 + e] = vh[0];
            hJ[(jb + 1) * 72 + e] = vh[1];
            hJ[(jb + 2) * 72 + e] = vh[2];
            hJ[(jb + 3) * 72 + e] = vh[3];
            if (wantT) *(half4_*)(hT + e * 72 + jb) = vh;
        }
    };
    // static acc indexing (wave-uniform branch; rule #20)
    auto combine_epi = [&](const float* bs, _Float16* hJ, _Float16* hT,
                           bool wantT) {
        if (kh == 0) { xr(acc[0]); epi_rows(acc[0], bs, hJ, hT, wantT); }
        else         { xr(acc[1]); epi_rows(acc[1], bs, hJ, hT, wantT); }
    };

    // ---- phase 0 ----
    sgemm(R_B, 32, S0);                          // S0 = x @ x^T (B from xJ)
    kloop_t<32, 0, 40>(acc, Wt0, R_A, sX, lr, q, ms, kh);
    if (kh == 0) xw(acc[1]); else xw(acc[0]);
    __syncthreads();                             // B1
    combine_epi(bs0, R_A, R_B, true);            // hJ1 -> R_A, hT1 -> R_B
    __syncthreads();                             // B2
    // ---- phase 1 ----
    sgemm(R_A, 64, S1);                          // S1 = x @ h1^T
    kloop_t<64, 1, 72>(acc, Wt1, R_B, sX, lr, q, ms, kh);
    if (kh == 0) xw(acc[1]); else xw(acc[0]);
    __syncthreads();                             // B3
    combine_epi(bs1, R_B, nullptr, false);       // hJ2 -> R_B
    __syncthreads();                             // B4
    sgemm(R_B, 64, S2);                          // S2 = x @ h2^T
}

// Direct-output GEMM: out[b, ob+k] = S_l[b,:] . Wt_l[:, dm0+k] + 64*bias.
// 1024 tasks, 1 task/block, 4-way K-split across waves; wave 0 combines.
__global__ __launch_bounds__(256, 4)
void cin_direct(const _Float16* __restrict__ S0v, const _Float16* __restrict__ S1v,
                const _Float16* __restrict__ S2v,
                const _Float16* __restrict__ Wt0, const _Float16* __restrict__ Wt1,
                const _Float16* __restrict__ Wt2,
                const float* __restrict__ bs0, const float* __restrict__ bs1,
                const float* __restrict__ bs2,
                float* __restrict__ out)
{
    __shared__ f32x4 red[3][64];
    const int t = threadIdx.x, lane = t & 63, kh = t >> 6;
    const int lr = lane & 15, q = lane >> 4;
    const int task = blockIdx.x;

    const _Float16 *S, *Wt;
    const float* bias;
    int fan, nch, dm0, ob, idx;
    if (task < 256)      { S = S0v; Wt = Wt0; bias = bs0; fan = 1024; nch = 32; dm0 = 64; ob = 0;   idx = task; }
    else if (task < 512) { S = S1v; Wt = Wt1; bias = bs1; fan = 2048; nch = 64; dm0 = 64; ob = 64;  idx = task - 256; }
    else                 { S = S2v; Wt = Wt2; bias = bs2; fan = 2048; nch = 64; dm0 = 0;  ob = 128; idx = task - 512; }
    const int bt = idx & 63, kt = idx >> 6;
    const int bbase = bt * 16;
    const int hq = nch >> 2, c0 = kh * hq;

    const _Float16* aG = Wt + (size_t)(dm0 + kt * 16 + lr) * 32 + q * 8
                            + (size_t)c0 * 4096;
    const _Float16* bG = S + (size_t)(bbase + lr) * fan + q * 8 + c0 * 32;

    f32x4 acc = {0.0f, 0.0f, 0.0f, 0.0f};
    half8 aA = *(const half8*)(aG);
    half8 bA = *(const half8*)(bG);
    for (int c = 0; c < hq; c += 2) {
        half8 aB = *(const half8*)(aG + (size_t)(c + 1) * 4096);
        half8 bB = *(const half8*)(bG + (c + 1) * 32);
        acc = __builtin_amdgcn_mfma_f32_16x16x32_f16(aA, bA, acc, 0, 0, 0);
        if (c + 2 < hq) {
            aA = *(const half8*)(aG + (size_t)(c + 2) * 4096);
            bA = *(const half8*)(bG + (c + 2) * 32);
        }
        acc = __builtin_amdgcn_mfma_f32_16x16x32_f16(aB, bB, acc, 0, 0, 0);
    }
    if (kh != 0) red[kh - 1][lane] = acc;
    __syncthreads();
    if (kh == 0) {
#pragma unroll
        for (int p = 0; p < 3; ++p) {
            f32x4 o = red[p][lane];
#pragma unroll
            for (int r = 0; r < 4; ++r) acc[r] += o[r];
        }
#pragma unroll
        for (int r = 0; r < 4; ++r) {
            int kl = kt * 16 + q * 4 + r;
            out[(size_t)(bbase + lr) * 256 + ob + kl]
                = acc[r] + 64.0f * bias[dm0 + kl];
        }
    }
}

extern "C" void kernel_launch(void* const* d_in, const int* in_sizes, int n_in,
                              void* d_out, int out_size, void* d_ws, size_t ws_size,
                              hipStream_t stream)
{
    const float* x  = (const float*)d_in[0];
    const float* W0 = (const float*)d_in[1];
    const float* b0 = (const float*)d_in[2];
    const float* W1 = (const float*)d_in[3];
    const float* b1 = (const float*)d_in[4];
    const float* W2 = (const float*)d_in[5];
    const float* b2 = (const float*)d_in[6];
    float* out = (float*)d_out;

    char* ws = (char*)d_ws;
    _Float16* Wt0 = (_Float16*)(ws + 0);           // 256 KB
    _Float16* Wt1 = (_Float16*)(ws + 262144);      // 512 KB
    _Float16* Wt2 = (_Float16*)(ws + 786432);      // 512 KB
    _Float16* S0  = (_Float16*)(ws + 1310720);     // 2 MB  (1024 x 1024 f16)
    _Float16* S1  = (_Float16*)(ws + 3407872);     // 4 MB  (1024 x 2048 f16)
    _Float16* S2  = (_Float16*)(ws + 7602176);     // 4 MB
    (void)in_sizes; (void)n_in; (void)out_size; (void)ws_size;

    hipLaunchKernelGGL(pack_w_all, dim3(160), dim3(256), 0, stream,
                       W0, Wt0, W1, Wt1, W2, Wt2);

    hipLaunchKernelGGL(cin_fused, dim3(1024), dim3(256), 0, stream,
                       x, Wt0, Wt1, b0, b1, S0, S1, S2);

    hipLaunchKernelGGL(cin_direct, dim3(1024), dim3(256), 0, stream,
                       S0, S1, S2, Wt0, Wt1, Wt2, b0, b1, b2, out);
}

// Round 7
// 115.495 us; speedup vs baseline: 1.2198x; 1.2198x over previous
//
#include <hip/hip_runtime.h>
#include <cstdint>

// CIN chain: B=1024, F0=32, EMB=64, layers 128/128/128.
// cur[b,k,e] = sum_{i,j} x[b,i,e]*h[b,j,e]*W[i*fi+j,k]
//
// R20b: resubmit of R20 (container infra failure, no counters).
// K-SPLIT-4 WITH THE PROVEN mt=4 KLOOP. Evidence so far:
//  * clean codegen configs: R14/R17 = mt=4, named aF frags, K-split-2
//    (VALU 11-15%, VGPR 88-92). Dirty: R16/R18/R19 = mt=2 4-wave
//    hybrids (VALU 37-50%) — which also violated rule #20 via
//    aF[it] runtime register indexing.
//  * 256-thr blocks write clean (WRITE=10240 KB exactly, R19);
//    128-thr amplify 9x.
//  * occupancy so far capped at 8 waves/CU (grid or LDS).
// This round: 1 batch/block, grid 1024, 256 thr = 4 waves, each wave
// = full mt=4 kloop over a K-QUARTER (c0 = w*NCH/4). aF0/aF1 are
// named registers loaded from a wave-uniform address (it=w&1 folds
// into the address, never an index). 4-way combine through a
// dedicated 24 KB f16 exchange region (12 slots of 1024 f16,
// contiguous 16 B/lane writes, conflict-free), one barrier; all acc
// indices static via 4-way wave-uniform branch. LDS 47104 B ->
// 3 blocks/CU = 12 waves/CU. Same 5-barrier skeleton as R14.
// LDS: sX 4K | R_A 9216 | R_B 9216 | XC 24K
//   R_A hT0(p40) -> [B1] -> hJ1(p72) -> [B3] -> hJ2(p72)
//   R_B xJ(p72)  -> [B1] -> hT1(p72)
//   XC  dedicated exchange (no aliasing)

typedef _Float16 half8  __attribute__((ext_vector_type(8)));
typedef _Float16 half4_ __attribute__((ext_vector_type(4)));
typedef _Float16 half2_ __attribute__((ext_vector_type(2)));
typedef float    f32x4  __attribute__((ext_vector_type(4)));

// Pack W (fan_in,128) f32 -> chunked f16 Wt[c][m][kk] = W[c*32+kk][m].
__global__ void pack_w_all(const float* __restrict__ W0, _Float16* __restrict__ Wt0,
                           const float* __restrict__ W1, _Float16* __restrict__ Wt1,
                           const float* __restrict__ W2, _Float16* __restrict__ Wt2)
{
    __shared__ _Float16 ldsT[128 * 33];
    const int blk = blockIdx.x, t = threadIdx.x;
    const float* W;
    _Float16* Wt;
    int c;
    if (blk < 32)       { W = W0; Wt = Wt0; c = blk; }
    else if (blk < 96)  { W = W1; Wt = Wt1; c = blk - 32; }
    else                { W = W2; Wt = Wt2; c = blk - 96; }

    for (int p = t; p < 32 * 128; p += 256) {
        int kk = p >> 7, m = p & 127;
        ldsT[m * 33 + kk] = (_Float16)W[(size_t)(c * 32 + kk) * 128 + m];
    }
    __syncthreads();
    int m = t >> 1, kk0 = (t & 1) * 16;
    half8 v0, v1;
#pragma unroll
    for (int i = 0; i < 8; ++i) {
        v0[i] = ldsT[m * 33 + kk0 + i];
        v1[i] = ldsT[m * 33 + kk0 + 8 + i];
    }
    *(half8*)(Wt + (size_t)c * 4096 + t * 16)     = v0;
    *(half8*)(Wt + (size_t)c * 4096 + t * 16 + 8) = v1;
}

// Templated kloop: ALL 64 hidden rows (mt=4), this wave's K-quarter.
template<int NCH, int ISH, int PH>
__device__ __forceinline__ void kloop_t(f32x4 (&acc)[4][4],
    const _Float16* __restrict__ WtL, const _Float16* __restrict__ hb,
    const _Float16* __restrict__ sX, int lr, int q, int w)
{
#pragma unroll
    for (int mt = 0; mt < 4; ++mt)
#pragma unroll
        for (int nt = 0; nt < 4; ++nt)
            acc[mt][nt] = f32x4{0.0f, 0.0f, 0.0f, 0.0f};

    constexpr int HC = NCH / 4;               // chunks per wave
    const int c0 = w * HC;
    const _Float16* aG = WtL + (size_t)c0 * 4096 + lr * 32 + q * 8;
    const _Float16* hP = hb + lr * PH + q * 8;
    const _Float16* xP = sX + lr;

    half8 afA[4], afB[4], hvA[4], hvB[4];
    _Float16 xsA[4], xsB[4];

    auto pf = [&](half8* af, half8* hv, _Float16* xs, int cc) {
        const int c  = c0 + cc;
        const int i  = c >> ISH;
        const int j0 = (c & ((1 << ISH) - 1)) << 5;
        const _Float16* ag = aG + (size_t)cc * 4096;
#pragma unroll
        for (int mt = 0; mt < 4; ++mt)
            af[mt] = *(const half8*)(ag + mt * 512);
        const _Float16* hh = hP + j0;
        const _Float16* xb = xP + (i << 6);
#pragma unroll
        for (int nt = 0; nt < 4; ++nt) {
            hv[nt] = *(const half8*)(hh + nt * (PH * 16));
            xs[nt] = xb[nt * 16];
        }
    };
    auto cp = [&](half8* af, half8* hv, _Float16* xs) {
#pragma unroll
        for (int nt = 0; nt < 4; ++nt) {
            half2_ xv2 = {xs[nt], xs[nt]};
            half8 xv8 = __builtin_shufflevector(xv2, xv2, 0, 1, 0, 1, 0, 1, 0, 1);
            half8 bf = hv[nt] * xv8;
#pragma unroll
            for (int mt = 0; mt < 4; ++mt)
                acc[mt][nt] = __builtin_amdgcn_mfma_f32_16x16x32_f16(
                    af[mt], bf, acc[mt][nt], 0, 0, 0);
        }
    };

    pf(afA, hvA, xsA, 0);
    for (int cc = 0; cc < HC; cc += 2) {
        pf(afB, hvB, xsB, cc + 1);
        cp(afA, hvA, xsA);
        if (cc + 2 < HC) pf(afA, hvA, xsA, cc + 2);
        cp(afB, hvB, xsB);
    }
}

// Fused hidden+S kernel. Block = 1 batch, 256 thr = 4 waves (K-quarter w).
__global__ __launch_bounds__(256, 2)
void cin_fused(const float* __restrict__ x,          // (1024,32,64) f32
               const _Float16* __restrict__ Wt0,
               const _Float16* __restrict__ Wt1,
               const float* __restrict__ bs0,
               const float* __restrict__ bs1,
               _Float16* __restrict__ S0,             // (1024,1024)
               _Float16* __restrict__ S1,             // (1024,2048)
               _Float16* __restrict__ S2)             // (1024,2048)
{
    __shared__ alignas(16) char smem[47104];
    _Float16* sX   = (_Float16*)smem;                  // 4 KB  [i*64+e]
    _Float16* R_A  = (_Float16*)(smem + 4096);         // 9216 B
    _Float16* R_B  = (_Float16*)(smem + 13312);        // 9216 B
    _Float16* XC16 = (_Float16*)(smem + 22528);        // 24 KB exchange

    const int t = threadIdx.x, lane = t & 63, w = t >> 6;
    const int lr = lane & 15, q = lane >> 4;
    const int b = blockIdx.x;

    // prologue: x -> sX [i][e]; xJ (pitch 72) -> R_B; hT0 (pitch 40) -> R_A
    {
        const float4* xv = (const float4*)(x + (size_t)b * 2048);
#pragma unroll
        for (int s = 0; s < 2; ++s) {
            int p4 = t + s * 256;
            float4 v = xv[p4];
            int idx = p4 * 4, i = idx >> 6, e0 = idx & 63;
            _Float16 h0 = (_Float16)v.x, h1 = (_Float16)v.y;
            _Float16 h2 = (_Float16)v.z, h3 = (_Float16)v.w;
            half4_ pk = {h0, h1, h2, h3};
            *(half4_*)(sX + i * 64 + e0) = pk;
            *(half4_*)(R_B + i * 72 + e0) = pk;
            R_A[(e0 + 0) * 40 + i] = h0;
            R_A[(e0 + 1) * 40 + i] = h1;
            R_A[(e0 + 2) * 40 + i] = h2;
            R_A[(e0 + 3) * 40 + i] = h3;
        }
    }
    __syncthreads();                                   // B0

    // persistent sgemm A-fragments, NAMED (it = w&1 folds into address)
    const int it = w & 1;
    const half8 aF0 = *(const half8*)(R_B + (it * 16 + lr) * 72 + q * 8);
    const half8 aF1 = *(const half8*)(R_B + (it * 16 + lr) * 72 + q * 8 + 32);

    f32x4 acc[4][4];

    // 4-way exchange: wave w writes its 3 non-owned mt blocks as f16.
    // slot(writer w, mt) = mt*3 + (w>mt ? w-1 : w); reader of mt=w reads
    // slots w*3 .. w*3+2. 12 slots x 1024 f16 = 24 KB.
    auto xchg_write = [&]() {
#pragma unroll
        for (int mt = 0; mt < 4; ++mt) {
            if (mt == w) continue;                     // wave-uniform
            const int slot = mt * 3 + (w > mt ? w - 1 : w);
#pragma unroll
            for (int cc = 0; cc < 2; ++cc) {
                half8 hv8;
#pragma unroll
                for (int r = 0; r < 4; ++r) {
                    hv8[r]     = (_Float16)acc[mt][cc * 2][r];
                    hv8[4 + r] = (_Float16)acc[mt][cc * 2 + 1][r];
                }
                *(half8*)(XC16 + slot * 1024 + cc * 512 + lane * 8) = hv8;
            }
        }
    };

    // combine partials into aw (static ref) + epilogue of 16 rows
    auto finish = [&](f32x4 (&aw)[4], const float* bs,
                      _Float16* hJ, _Float16* hT, bool wantT) {
#pragma unroll
        for (int p = 0; p < 3; ++p) {
#pragma unroll
            for (int cc = 0; cc < 2; ++cc) {
                half8 hv8 = *(const half8*)(XC16 + (w * 3 + p) * 1024
                                            + cc * 512 + lane * 8);
#pragma unroll
                for (int r = 0; r < 4; ++r) {
                    aw[cc * 2][r]     += (float)hv8[r];
                    aw[cc * 2 + 1][r] += (float)hv8[4 + r];
                }
            }
        }
        const int jb = w * 16 + q * 4;
        const float b0f = bs[jb + 0], b1f = bs[jb + 1];
        const float b2f = bs[jb + 2], b3f = bs[jb + 3];
#pragma unroll
        for (int nt = 0; nt < 4; ++nt) {
            const int e = nt * 16 + lr;
            half4_ vh;
            vh[0] = (_Float16)(aw[nt][0] + b0f);
            vh[1] = (_Float16)(aw[nt][1] + b1f);
            vh[2] = (_Float16)(aw[nt][2] + b2f);
            vh[3] = (_Float16)(aw[nt][3] + b3f);
            hJ[(jb + 0) * 72 + e] = vh[0];
            hJ[(jb + 1) * 72 + e] = vh[1];
            hJ[(jb + 2) * 72 + e] = vh[2];
            hJ[(jb + 3) * 72 + e] = vh[3];
            if (wantT) *(half4_*)(hT + e * 72 + jb) = vh;
        }
    };
    auto combine_epi = [&](const float* bs, _Float16* hJ, _Float16* hT,
                           bool wantT) {
        if (w == 0)      finish(acc[0], bs, hJ, hT, wantT);
        else if (w == 1) finish(acc[1], bs, hJ, hT, wantT);
        else if (w == 2) finish(acc[2], bs, hJ, hT, wantT);
        else             finish(acc[3], bs, hJ, hT, wantT);
    };

    // S_l[b][i*fi+j] = sum_e x[i,e]*h[j,e]; tiles split across 4 waves,
    // this wave's i-tile fixed = it (aF0/aF1), jt varies.
    auto sgemm = [&](const _Float16* hJ, int fi, _Float16* Sdst) {
        const int nT = fi >> 3;                        // 4 or 8 tiles
        for (int tt = w; tt < nT; tt += 4) {
            const int jt = tt >> 1;
            f32x4 sa = {0.0f, 0.0f, 0.0f, 0.0f};
            half8 bv0 = *(const half8*)(hJ + (jt * 16 + lr) * 72 + q * 8);
            half8 bv1 = *(const half8*)(hJ + (jt * 16 + lr) * 72 + q * 8 + 32);
            sa = __builtin_amdgcn_mfma_f32_16x16x32_f16(aF0, bv0, sa, 0, 0, 0);
            sa = __builtin_amdgcn_mfma_f32_16x16x32_f16(aF1, bv1, sa, 0, 0, 0);
#pragma unroll
            for (int r = 0; r < 4; ++r)
                Sdst[(size_t)b * (32 * fi) + (it * 16 + q * 4 + r) * fi
                     + jt * 16 + lr] = (_Float16)sa[r];
        }
    };

    // ---- phase 0 ----
    sgemm(R_B, 32, S0);                          // S0 = x @ x^T (B from xJ)
    kloop_t<32, 0, 40>(acc, Wt0, R_A, sX, lr, q, w);
    xchg_write();
    __syncthreads();                             // B1
    combine_epi(bs0, R_A, R_B, true);            // hJ1 -> R_A, hT1 -> R_B
    __syncthreads();                             // B2
    // ---- phase 1 ----
    sgemm(R_A, 64, S1);                          // S1 = x @ h1^T
    kloop_t<64, 1, 72>(acc, Wt1, R_B, sX, lr, q, w);
    xchg_write();
    __syncthreads();                             // B3
    combine_epi(bs1, R_A, nullptr, false);       // hJ2 -> R_A (hJ1 dead)
    __syncthreads();                             // B4
    sgemm(R_A, 64, S2);                          // S2 = x @ h2^T
}

// Direct-output GEMM: out[b, ob+k] = S_l[b,:] . Wt_l[:, dm0+k] + 64*bias.
// 1024 tasks, 1 task/block, 4-way K-split across waves; wave 0 combines.
__global__ __launch_bounds__(256, 4)
void cin_direct(const _Float16* __restrict__ S0v, const _Float16* __restrict__ S1v,
                const _Float16* __restrict__ S2v,
                const _Float16* __restrict__ Wt0, const _Float16* __restrict__ Wt1,
                const _Float16* __restrict__ Wt2,
                const float* __restrict__ bs0, const float* __restrict__ bs1,
                const float* __restrict__ bs2,
                float* __restrict__ out)
{
    __shared__ f32x4 red[3][64];
    const int t = threadIdx.x, lane = t & 63, kh = t >> 6;
    const int lr = lane & 15, q = lane >> 4;
    const int task = blockIdx.x;

    const _Float16 *S, *Wt;
    const float* bias;
    int fan, nch, dm0, ob, idx;
    if (task < 256)      { S = S0v; Wt = Wt0; bias = bs0; fan = 1024; nch = 32; dm0 = 64; ob = 0;   idx = task; }
    else if (task < 512) { S = S1v; Wt = Wt1; bias = bs1; fan = 2048; nch = 64; dm0 = 64; ob = 64;  idx = task - 256; }
    else                 { S = S2v; Wt = Wt2; bias = bs2; fan = 2048; nch = 64; dm0 = 0;  ob = 128; idx = task - 512; }
    const int bt = idx & 63, kt = idx >> 6;
    const int bbase = bt * 16;
    const int hq = nch >> 2, c0 = kh * hq;

    const _Float16* aG = Wt + (size_t)(dm0 + kt * 16 + lr) * 32 + q * 8
                            + (size_t)c0 * 4096;
    const _Float16* bG = S + (size_t)(bbase + lr) * fan + q * 8 + c0 * 32;

    f32x4 acc = {0.0f, 0.0f, 0.0f, 0.0f};
    half8 aA = *(const half8*)(aG);
    half8 bA = *(const half8*)(bG);
    for (int c = 0; c < hq; c += 2) {
        half8 aB = *(const half8*)(aG + (size_t)(c + 1) * 4096);
        half8 bB = *(const half8*)(bG + (c + 1) * 32);
        acc = __builtin_amdgcn_mfma_f32_16x16x32_f16(aA, bA, acc, 0, 0, 0);
        if (c + 2 < hq) {
            aA = *(const half8*)(aG + (size_t)(c + 2) * 4096);
            bA = *(const half8*)(bG + (c + 2) * 32);
        }
        acc = __builtin_amdgcn_mfma_f32_16x16x32_f16(aB, bB, acc, 0, 0, 0);
    }
    if (kh != 0) red[kh - 1][lane] = acc;
    __syncthreads();
    if (kh == 0) {
#pragma unroll
        for (int p = 0; p < 3; ++p) {
            f32x4 o = red[p][lane];
#pragma unroll
            for (int r = 0; r < 4; ++r) acc[r] += o[r];
        }
#pragma unroll
        for (int r = 0; r < 4; ++r) {
            int kl = kt * 16 + q * 4 + r;
            out[(size_t)(bbase + lr) * 256 + ob + kl]
                = acc[r] + 64.0f * bias[dm0 + kl];
        }
    }
}

extern "C" void kernel_launch(void* const* d_in, const int* in_sizes, int n_in,
                              void* d_out, int out_size, void* d_ws, size_t ws_size,
                              hipStream_t stream)
{
    const float* x  = (const float*)d_in[0];
    const float* W0 = (const float*)d_in[1];
    const float* b0 = (const float*)d_in[2];
    const float* W1 = (const float*)d_in[3];
    const float* b1 = (const float*)d_in[4];
    const float* W2 = (const float*)d_in[5];
    const float* b2 = (const float*)d_in[6];
    float* out = (float*)d_out;

    char* ws = (char*)d_ws;
    _Float16* Wt0 = (_Float16*)(ws + 0);           // 256 KB
    _Float16* Wt1 = (_Float16*)(ws + 262144);      // 512 KB
    _Float16* Wt2 = (_Float16*)(ws + 786432);      // 512 KB
    _Float16* S0  = (_Float16*)(ws + 1310720);     // 2 MB  (1024 x 1024 f16)
    _Float16* S1  = (_Float16*)(ws + 3407872);     // 4 MB  (1024 x 2048 f16)
    _Float16* S2  = (_Float16*)(ws + 7602176);     // 4 MB
    (void)in_sizes; (void)n_in; (void)out_size; (void)ws_size;

    hipLaunchKernelGGL(pack_w_all, dim3(160), dim3(256), 0, stream,
                       W0, Wt0, W1, Wt1, W2, Wt2);

    hipLaunchKernelGGL(cin_fused, dim3(1024), dim3(256), 0, stream,
                       x, Wt0, Wt1, b0, b1, S0, S1, S2);

    hipLaunchKernelGGL(cin_direct, dim3(1024), dim3(256), 0, stream,
                       S0, S1, S2, Wt0, Wt1, Wt2, b0, b1, b2, out);
}

// Round 8
// 114.633 us; speedup vs baseline: 1.2290x; 1.0075x over previous
//
#include <hip/hip_runtime.h>
#include <cstdint>

// CIN chain: B=1024, F0=32, EMB=64, layers 128/128/128.
// cur[b,k,e] = sum_{i,j} x[b,i,e]*h[b,j,e]*W[i*fi+j,k]
//
// R21: DEEPER af PREFETCH + setprio. R20b (115.5 us, best) fixed the
// VALU pathology (mt=4, named frags, K-split-4). Remaining fused gap
// vs ~12 us floor (L2 Wt traffic 393 MB = 11.4 us, MFMA 2.4 us) is
// latency/schedule: af global loads were only ~1 MFMA-body (78 cy) in
// flight vs 200-400 cy L2 latency. Changes (kloop only):
//  * af prefetch: 2-slot dist-1 -> 4-slot rotation, issue distance 2
//    bodies (~155 cy in flight). +32 VGPR; per m69 occupancy halves at
//    128/256 so likely bracket-neutral.
//  * s_setprio(1) around each 16-MFMA cluster: 3 independent blocks/CU
//    at different phases = wave role diversity (attn-like T5 regime).
//  * hv/xs stay 2-slot dist-1 (LDS short-latency); direct/pack
//    untouched.
// LDS: sX 4K | R_A 9216 | R_B 9216 | XC 24K  (47104 B, 3 blocks/CU)
//   R_A hT0(p40) -> [B1] -> hJ1(p72) -> [B3] -> hJ2(p72)
//   R_B xJ(p72)  -> [B1] -> hT1(p72)

typedef _Float16 half8  __attribute__((ext_vector_type(8)));
typedef _Float16 half4_ __attribute__((ext_vector_type(4)));
typedef _Float16 half2_ __attribute__((ext_vector_type(2)));
typedef float    f32x4  __attribute__((ext_vector_type(4)));

// Pack W (fan_in,128) f32 -> chunked f16 Wt[c][m][kk] = W[c*32+kk][m].
__global__ void pack_w_all(const float* __restrict__ W0, _Float16* __restrict__ Wt0,
                           const float* __restrict__ W1, _Float16* __restrict__ Wt1,
                           const float* __restrict__ W2, _Float16* __restrict__ Wt2)
{
    __shared__ _Float16 ldsT[128 * 33];
    const int blk = blockIdx.x, t = threadIdx.x;
    const float* W;
    _Float16* Wt;
    int c;
    if (blk < 32)       { W = W0; Wt = Wt0; c = blk; }
    else if (blk < 96)  { W = W1; Wt = Wt1; c = blk - 32; }
    else                { W = W2; Wt = Wt2; c = blk - 96; }

    for (int p = t; p < 32 * 128; p += 256) {
        int kk = p >> 7, m = p & 127;
        ldsT[m * 33 + kk] = (_Float16)W[(size_t)(c * 32 + kk) * 128 + m];
    }
    __syncthreads();
    int m = t >> 1, kk0 = (t & 1) * 16;
    half8 v0, v1;
#pragma unroll
    for (int i = 0; i < 8; ++i) {
        v0[i] = ldsT[m * 33 + kk0 + i];
        v1[i] = ldsT[m * 33 + kk0 + 8 + i];
    }
    *(half8*)(Wt + (size_t)c * 4096 + t * 16)     = v0;
    *(half8*)(Wt + (size_t)c * 4096 + t * 16 + 8) = v1;
}

// Templated kloop: ALL 64 hidden rows (mt=4), this wave's K-quarter.
// af: 4-slot rotation, issue distance 2 bodies. hv/xs: 2-slot, dist 1.
template<int NCH, int ISH, int PH>
__device__ __forceinline__ void kloop_t(f32x4 (&acc)[4][4],
    const _Float16* __restrict__ WtL, const _Float16* __restrict__ hb,
    const _Float16* __restrict__ sX, int lr, int q, int w)
{
#pragma unroll
    for (int mt = 0; mt < 4; ++mt)
#pragma unroll
        for (int nt = 0; nt < 4; ++nt)
            acc[mt][nt] = f32x4{0.0f, 0.0f, 0.0f, 0.0f};

    constexpr int HC = NCH / 4;               // chunks per wave (8 or 16)
    const int c0 = w * HC;
    const _Float16* aG = WtL + (size_t)c0 * 4096 + lr * 32 + q * 8;
    const _Float16* hP = hb + lr * PH + q * 8;
    const _Float16* xP = sX + lr;

    half8 afA[4], afB[4], afC[4], afD[4], hvA[4], hvB[4];
    _Float16 xsA[4], xsB[4];

    auto pfa = [&](half8* af, int cc) {
        const _Float16* ag = aG + (size_t)cc * 4096;
#pragma unroll
        for (int mt = 0; mt < 4; ++mt)
            af[mt] = *(const half8*)(ag + mt * 512);
    };
    auto pfh = [&](half8* hv, _Float16* xs, int cc) {
        const int c  = c0 + cc;
        const int i  = c >> ISH;
        const int j0 = (c & ((1 << ISH) - 1)) << 5;
        const _Float16* hh = hP + j0;
        const _Float16* xb = xP + (i << 6);
#pragma unroll
        for (int nt = 0; nt < 4; ++nt) {
            hv[nt] = *(const half8*)(hh + nt * (PH * 16));
            xs[nt] = xb[nt * 16];
        }
    };
    auto cp = [&](half8* af, half8* hv, _Float16* xs) {
        __builtin_amdgcn_s_setprio(1);
#pragma unroll
        for (int nt = 0; nt < 4; ++nt) {
            half2_ xv2 = {xs[nt], xs[nt]};
            half8 xv8 = __builtin_shufflevector(xv2, xv2, 0, 1, 0, 1, 0, 1, 0, 1);
            half8 bf = hv[nt] * xv8;
#pragma unroll
            for (int mt = 0; mt < 4; ++mt)
                acc[mt][nt] = __builtin_amdgcn_mfma_f32_16x16x32_f16(
                    af[mt], bf, acc[mt][nt], 0, 0, 0);
        }
        __builtin_amdgcn_s_setprio(0);
    };

    pfa(afA, 0); pfa(afB, 1);
    pfh(hvA, xsA, 0);
    for (int cc = 0; cc < HC; cc += 4) {
        pfa(afC, cc + 2);
        pfh(hvB, xsB, cc + 1);
        cp(afA, hvA, xsA);                    // body cc
        pfa(afD, cc + 3);
        pfh(hvA, xsA, cc + 2);
        cp(afB, hvB, xsB);                    // body cc+1
        if (cc + 4 < HC) pfa(afA, cc + 4);
        pfh(hvB, xsB, cc + 3);
        cp(afC, hvA, xsA);                    // body cc+2
        if (cc + 5 < HC) pfa(afB, cc + 5);
        if (cc + 4 < HC) pfh(hvA, xsA, cc + 4);
        cp(afD, hvB, xsB);                    // body cc+3
    }
}

// Fused hidden+S kernel. Block = 1 batch, 256 thr = 4 waves (K-quarter w).
__global__ __launch_bounds__(256, 2)
void cin_fused(const float* __restrict__ x,          // (1024,32,64) f32
               const _Float16* __restrict__ Wt0,
               const _Float16* __restrict__ Wt1,
               const float* __restrict__ bs0,
               const float* __restrict__ bs1,
               _Float16* __restrict__ S0,             // (1024,1024)
               _Float16* __restrict__ S1,             // (1024,2048)
               _Float16* __restrict__ S2)             // (1024,2048)
{
    __shared__ alignas(16) char smem[47104];
    _Float16* sX   = (_Float16*)smem;                  // 4 KB  [i*64+e]
    _Float16* R_A  = (_Float16*)(smem + 4096);         // 9216 B
    _Float16* R_B  = (_Float16*)(smem + 13312);        // 9216 B
    _Float16* XC16 = (_Float16*)(smem + 22528);        // 24 KB exchange

    const int t = threadIdx.x, lane = t & 63, w = t >> 6;
    const int lr = lane & 15, q = lane >> 4;
    const int b = blockIdx.x;

    // prologue: x -> sX [i][e]; xJ (pitch 72) -> R_B; hT0 (pitch 40) -> R_A
    {
        const float4* xv = (const float4*)(x + (size_t)b * 2048);
#pragma unroll
        for (int s = 0; s < 2; ++s) {
            int p4 = t + s * 256;
            float4 v = xv[p4];
            int idx = p4 * 4, i = idx >> 6, e0 = idx & 63;
            _Float16 h0 = (_Float16)v.x, h1 = (_Float16)v.y;
            _Float16 h2 = (_Float16)v.z, h3 = (_Float16)v.w;
            half4_ pk = {h0, h1, h2, h3};
            *(half4_*)(sX + i * 64 + e0) = pk;
            *(half4_*)(R_B + i * 72 + e0) = pk;
            R_A[(e0 + 0) * 40 + i] = h0;
            R_A[(e0 + 1) * 40 + i] = h1;
            R_A[(e0 + 2) * 40 + i] = h2;
            R_A[(e0 + 3) * 40 + i] = h3;
        }
    }
    __syncthreads();                                   // B0

    // persistent sgemm A-fragments, NAMED (it = w&1 folds into address)
    const int it = w & 1;
    const half8 aF0 = *(const half8*)(R_B + (it * 16 + lr) * 72 + q * 8);
    const half8 aF1 = *(const half8*)(R_B + (it * 16 + lr) * 72 + q * 8 + 32);

    f32x4 acc[4][4];

    // 4-way exchange: wave w writes its 3 non-owned mt blocks as f16.
    // slot(writer w, mt) = mt*3 + (w>mt ? w-1 : w); reader of mt=w reads
    // slots w*3 .. w*3+2. 12 slots x 1024 f16 = 24 KB.
    auto xchg_write = [&]() {
#pragma unroll
        for (int mt = 0; mt < 4; ++mt) {
            if (mt == w) continue;                     // wave-uniform
            const int slot = mt * 3 + (w > mt ? w - 1 : w);
#pragma unroll
            for (int cc = 0; cc < 2; ++cc) {
                half8 hv8;
#pragma unroll
                for (int r = 0; r < 4; ++r) {
                    hv8[r]     = (_Float16)acc[mt][cc * 2][r];
                    hv8[4 + r] = (_Float16)acc[mt][cc * 2 + 1][r];
                }
                *(half8*)(XC16 + slot * 1024 + cc * 512 + lane * 8) = hv8;
            }
        }
    };

    // combine partials into aw (static ref) + epilogue of 16 rows
    auto finish = [&](f32x4 (&aw)[4], const float* bs,
                      _Float16* hJ, _Float16* hT, bool wantT) {
#pragma unroll
        for (int p = 0; p < 3; ++p) {
#pragma unroll
            for (int cc = 0; cc < 2; ++cc) {
                half8 hv8 = *(const half8*)(XC16 + (w * 3 + p) * 1024
                                            + cc * 512 + lane * 8);
#pragma unroll
                for (int r = 0; r < 4; ++r) {
                    aw[cc * 2][r]     += (float)hv8[r];
                    aw[cc * 2 + 1][r] += (float)hv8[4 + r];
                }
            }
        }
        const int jb = w * 16 + q * 4;
        const float b0f = bs[jb + 0], b1f = bs[jb + 1];
        const float b2f = bs[jb + 2], b3f = bs[jb + 3];
#pragma unroll
        for (int nt = 0; nt < 4; ++nt) {
            const int e = nt * 16 + lr;
            half4_ vh;
            vh[0] = (_Float16)(aw[nt][0] + b0f);
            vh[1] = (_Float16)(aw[nt][1] + b1f);
            vh[2] = (_Float16)(aw[nt][2] + b2f);
            vh[3] = (_Float16)(aw[nt][3] + b3f);
            hJ[(jb + 0) * 72 + e] = vh[0];
            hJ[(jb + 1) * 72 + e] = vh[1];
            hJ[(jb + 2) * 72 + e] = vh[2];
            hJ[(jb + 3) * 72 + e] = vh[3];
            if (wantT) *(half4_*)(hT + e * 72 + jb) = vh;
        }
    };
    auto combine_epi = [&](const float* bs, _Float16* hJ, _Float16* hT,
                           bool wantT) {
        if (w == 0)      finish(acc[0], bs, hJ, hT, wantT);
        else if (w == 1) finish(acc[1], bs, hJ, hT, wantT);
        else if (w == 2) finish(acc[2], bs, hJ, hT, wantT);
        else             finish(acc[3], bs, hJ, hT, wantT);
    };

    // S_l[b][i*fi+j] = sum_e x[i,e]*h[j,e]; tiles split across 4 waves,
    // this wave's i-tile fixed = it (aF0/aF1), jt varies.
    auto sgemm = [&](const _Float16* hJ, int fi, _Float16* Sdst) {
        const int nT = fi >> 3;                        // 4 or 8 tiles
        for (int tt = w; tt < nT; tt += 4) {
            const int jt = tt >> 1;
            f32x4 sa = {0.0f, 0.0f, 0.0f, 0.0f};
            half8 bv0 = *(const half8*)(hJ + (jt * 16 + lr) * 72 + q * 8);
            half8 bv1 = *(const half8*)(hJ + (jt * 16 + lr) * 72 + q * 8 + 32);
            sa = __builtin_amdgcn_mfma_f32_16x16x32_f16(aF0, bv0, sa, 0, 0, 0);
            sa = __builtin_amdgcn_mfma_f32_16x16x32_f16(aF1, bv1, sa, 0, 0, 0);
#pragma unroll
            for (int r = 0; r < 4; ++r)
                Sdst[(size_t)b * (32 * fi) + (it * 16 + q * 4 + r) * fi
                     + jt * 16 + lr] = (_Float16)sa[r];
        }
    };

    // ---- phase 0 ----
    sgemm(R_B, 32, S0);                          // S0 = x @ x^T (B from xJ)
    kloop_t<32, 0, 40>(acc, Wt0, R_A, sX, lr, q, w);
    xchg_write();
    __syncthreads();                             // B1
    combine_epi(bs0, R_A, R_B, true);            // hJ1 -> R_A, hT1 -> R_B
    __syncthreads();                             // B2
    // ---- phase 1 ----
    sgemm(R_A, 64, S1);                          // S1 = x @ h1^T
    kloop_t<64, 1, 72>(acc, Wt1, R_B, sX, lr, q, w);
    xchg_write();
    __syncthreads();                             // B3
    combine_epi(bs1, R_A, nullptr, false);       // hJ2 -> R_A (hJ1 dead)
    __syncthreads();                             // B4
    sgemm(R_A, 64, S2);                          // S2 = x @ h2^T
}

// Direct-output GEMM: out[b, ob+k] = S_l[b,:] . Wt_l[:, dm0+k] + 64*bias.
// 1024 tasks, 1 task/block, 4-way K-split across waves; wave 0 combines.
__global__ __launch_bounds__(256, 4)
void cin_direct(const _Float16* __restrict__ S0v, const _Float16* __restrict__ S1v,
                const _Float16* __restrict__ S2v,
                const _Float16* __restrict__ Wt0, const _Float16* __restrict__ Wt1,
                const _Float16* __restrict__ Wt2,
                const float* __restrict__ bs0, const float* __restrict__ bs1,
                const float* __restrict__ bs2,
                float* __restrict__ out)
{
    __shared__ f32x4 red[3][64];
    const int t = threadIdx.x, lane = t & 63, kh = t >> 6;
    const int lr = lane & 15, q = lane >> 4;
    const int task = blockIdx.x;

    const _Float16 *S, *Wt;
    const float* bias;
    int fan, nch, dm0, ob, idx;
    if (task < 256)      { S = S0v; Wt = Wt0; bias = bs0; fan = 1024; nch = 32; dm0 = 64; ob = 0;   idx = task; }
    else if (task < 512) { S = S1v; Wt = Wt1; bias = bs1; fan = 2048; nch = 64; dm0 = 64; ob = 64;  idx = task - 256; }
    else                 { S = S2v; Wt = Wt2; bias = bs2; fan = 2048; nch = 64; dm0 = 0;  ob = 128; idx = task - 512; }
    const int bt = idx & 63, kt = idx >> 6;
    const int bbase = bt * 16;
    const int hq = nch >> 2, c0 = kh * hq;

    const _Float16* aG = Wt + (size_t)(dm0 + kt * 16 + lr) * 32 + q * 8
                            + (size_t)c0 * 4096;
    const _Float16* bG = S + (size_t)(bbase + lr) * fan + q * 8 + c0 * 32;

    f32x4 acc = {0.0f, 0.0f, 0.0f, 0.0f};
    half8 aA = *(const half8*)(aG);
    half8 bA = *(const half8*)(bG);
    for (int c = 0; c < hq; c += 2) {
        half8 aB = *(const half8*)(aG + (size_t)(c + 1) * 4096);
        half8 bB = *(const half8*)(bG + (c + 1) * 32);
        acc = __builtin_amdgcn_mfma_f32_16x16x32_f16(aA, bA, acc, 0, 0, 0);
        if (c + 2 < hq) {
            aA = *(const half8*)(aG + (size_t)(c + 2) * 4096);
            bA = *(const half8*)(bG + (c + 2) * 32);
        }
        acc = __builtin_amdgcn_mfma_f32_16x16x32_f16(aB, bB, acc, 0, 0, 0);
    }
    if (kh != 0) red[kh - 1][lane] = acc;
    __syncthreads();
    if (kh == 0) {
#pragma unroll
        for (int p = 0; p < 3; ++p) {
            f32x4 o = red[p][lane];
#pragma unroll
            for (int r = 0; r < 4; ++r) acc[r] += o[r];
        }
#pragma unroll
        for (int r = 0; r < 4; ++r) {
            int kl = kt * 16 + q * 4 + r;
            out[(size_t)(bbase + lr) * 256 + ob + kl]
                = acc[r] + 64.0f * bias[dm0 + kl];
        }
    }
}

extern "C" void kernel_launch(void* const* d_in, const int* in_sizes, int n_in,
                              void* d_out, int out_size, void* d_ws, size_t ws_size,
                              hipStream_t stream)
{
    const float* x  = (const float*)d_in[0];
    const float* W0 = (const float*)d_in[1];
    const float* b0 = (const float*)d_in[2];
    const float* W1 = (const float*)d_in[3];
    const float* b1 = (const float*)d_in[4];
    const float* W2 = (const float*)d_in[5];
    const float* b2 = (const float*)d_in[6];
    float* out = (float*)d_out;

    char* ws = (char*)d_ws;
    _Float16* Wt0 = (_Float16*)(ws + 0);           // 256 KB
    _Float16* Wt1 = (_Float16*)(ws + 262144);      // 512 KB
    _Float16* Wt2 = (_Float16*)(ws + 786432);      // 512 KB
    _Float16* S0  = (_Float16*)(ws + 1310720);     // 2 MB  (1024 x 1024 f16)
    _Float16* S1  = (_Float16*)(ws + 3407872);     // 4 MB  (1024 x 2048 f16)
    _Float16* S2  = (_Float16*)(ws + 7602176);     // 4 MB
    (void)in_sizes; (void)n_in; (void)out_size; (void)ws_size;

    hipLaunchKernelGGL(pack_w_all, dim3(160), dim3(256), 0, stream,
                       W0, Wt0, W1, Wt1, W2, Wt2);

    hipLaunchKernelGGL(cin_fused, dim3(1024), dim3(256), 0, stream,
                       x, Wt0, Wt1, b0, b1, S0, S1, S2);

    hipLaunchKernelGGL(cin_direct, dim3(1024), dim3(256), 0, stream,
                       S0, S1, S2, Wt0, Wt1, Wt2, b0, b1, b2, out);
}